// Round 9
// baseline (598.357 us; speedup 1.0000x reference)
//
#include <hip/hip_runtime.h>
#include <math.h>

#define N_NODES 100000
#define N_EDGES 1600000
#define IN_F    128
#define NH1     8
#define HID     8
#define C1      64   // NH1*HID
#define C2      40   // N_CLASSES
#define SCAN_B  256
#define N_SBLK  ((N_NODES + SCAN_B - 1) / SCAN_B)   // 391

typedef unsigned short ushort_t;
typedef unsigned int uint_t;
typedef _Float16 half_t;
typedef _Float16 half8 __attribute__((ext_vector_type(8)));

__device__ __forceinline__ float lrelu(float x) { return x > 0.f ? x : 0.2f * x; }
__device__ __forceinline__ ushort_t f2bf(float f) {
    uint_t u = __float_as_uint(f);
    u = (u + 0x7FFFu + ((u >> 16) & 1u)) >> 16;   // round-to-nearest-even
    return (ushort_t)u;
}
__device__ __forceinline__ float bf2f(ushort_t s) {
    return __uint_as_float(((uint_t)s) << 16);
}

// ---- K1: H1(bf16) = x@W1 ; s1[n,h], d1[n,h] attention dots. 4 nodes/block ----
__global__ __launch_bounds__(256) void k_gemm1(
    const float* __restrict__ x, const float* __restrict__ W1,
    const float* __restrict__ as1, const float* __restrict__ ad1,
    ushort_t* __restrict__ H1, float* __restrict__ s1, float* __restrict__ d1)
{
    __shared__ float xs[4][IN_F];
    int wv = threadIdx.x >> 6, lane = threadIdx.x & 63;
    int n = blockIdx.x * 4 + wv;
    ((float2*)xs[wv])[lane] = ((const float2*)(x + (size_t)n * IN_F))[lane];
    __syncthreads();
    float acc = 0.f;
    #pragma unroll
    for (int k = 0; k < IN_F; k += 4) {
        float4 xk = *(const float4*)&xs[wv][k];
        acc = fmaf(xk.x, W1[(k + 0) * C1 + lane], acc);
        acc = fmaf(xk.y, W1[(k + 1) * C1 + lane], acc);
        acc = fmaf(xk.z, W1[(k + 2) * C1 + lane], acc);
        acc = fmaf(xk.w, W1[(k + 3) * C1 + lane], acc);
    }
    H1[(size_t)n * C1 + lane] = f2bf(acc);
    float ps = acc * as1[lane], pd = acc * ad1[lane];  // lane == h*8+f
    #pragma unroll
    for (int off = 4; off; off >>= 1) {
        ps += __shfl_xor(ps, off);
        pd += __shfl_xor(pd, off);
    }
    if ((lane & 7) == 0) {
        s1[n * NH1 + (lane >> 3)] = ps;
        d1[n * NH1 + (lane >> 3)] = pd;
    }
}

// ---- CSR build: degree count + per-edge rank (old value of the counter) ----
__global__ __launch_bounds__(256) void k_count(
    const int* __restrict__ ei, int* __restrict__ deg, int* __restrict__ rank)
{
    int e = blockIdx.x * blockDim.x + threadIdx.x;
    if (e >= N_EDGES) return;
    rank[e] = atomicAdd(&deg[ei[N_EDGES + e]], 1);
}

// ---- scan phase 1: per-block (256-wide) reduction of deg -> bsum ----
__global__ __launch_bounds__(SCAN_B) void k_red(
    const int* __restrict__ deg, int* __restrict__ bsum)
{
    int t = threadIdx.x, lane = t & 63, wv = t >> 6;
    int i = blockIdx.x * SCAN_B + t;
    int v = (i < N_NODES) ? deg[i] : 0;
    #pragma unroll
    for (int off = 32; off; off >>= 1) v += __shfl_xor(v, off);
    __shared__ int s[4];
    if (lane == 0) s[wv] = v;
    __syncthreads();
    if (t == 0) bsum[blockIdx.x] = s[0] + s[1] + s[2] + s[3];
}

// ---- scan phase 2: single small block scans the 391 block sums ----
__global__ __launch_bounds__(512) void k_scan_small(
    const int* __restrict__ bsum, int* __restrict__ boff,
    int* __restrict__ rowptr)
{
    __shared__ int s[512];
    int t = threadIdx.x;
    int v = (t < N_SBLK) ? bsum[t] : 0;
    s[t] = v;
    __syncthreads();
    for (int off = 1; off < 512; off <<= 1) {
        int u = (t >= off) ? s[t - off] : 0;
        __syncthreads();
        s[t] += u;
        __syncthreads();
    }
    if (t < N_SBLK) boff[t] = s[t] - v;          // exclusive
    if (t == 511) rowptr[N_NODES] = s[511];      // total == N_EDGES
}

// ---- scan phase 3: in-block exclusive scan + block offset -> rowptr ----
__global__ __launch_bounds__(SCAN_B) void k_apply(
    const int* __restrict__ deg, const int* __restrict__ boff,
    int* __restrict__ rowptr)
{
    int t = threadIdx.x, lane = t & 63, wv = t >> 6;
    int i = blockIdx.x * SCAN_B + t;
    int v = (i < N_NODES) ? deg[i] : 0;
    int inc = v;
    #pragma unroll
    for (int off = 1; off < 64; off <<= 1) {
        int u = __shfl_up(inc, off);
        if (lane >= off) inc += u;
    }
    __shared__ int ws_[4];
    if (lane == 63) ws_[wv] = inc;
    __syncthreads();
    int add = 0;
    for (int k = 0; k < wv; k++) add += ws_[k];
    if (i < N_NODES) rowptr[i] = inc - v + add + boff[blockIdx.x];
}

// ---- CSR build: fill packed (src, w) — NO atomics, one 8-B store/edge ----
__global__ __launch_bounds__(256) void k_fill(
    const int* __restrict__ ei, const float* __restrict__ ea,
    const int* __restrict__ rowptr, const int* __restrict__ rank,
    int2* __restrict__ edges)
{
    int e = blockIdx.x * blockDim.x + threadIdx.x;
    if (e >= N_EDGES) return;
    int s = ei[e], d = ei[N_EDGES + e];
    int pos = rowptr[d] + rank[e];
    edges[pos] = make_int2(s, __float_as_int(ea[e]));
}

// ---- K_logit1: wave per dst node, lane = eL*8 + hL. p1 in SoA [8][E]:
//      p1s[h*E + pos] so node1 can read 8 consecutive positions per head
//      as one 16-B load. Writes: 16-B coalesced per head-group. ----
__global__ __launch_bounds__(256) void k_logit1(
    const int* __restrict__ rowptr, const int2* __restrict__ edges,
    const float* __restrict__ s1, const float* __restrict__ d1,
    const float* __restrict__ ae1, half_t* __restrict__ p1s)
{
    int w = (blockIdx.x * blockDim.x + threadIdx.x) >> 6;
    int lane = threadIdx.x & 63;
    if (w >= N_NODES) return;
    int hL = lane & 7, eL = lane >> 3;
    float d1L = d1[w * NH1 + hL];
    float aeL = ae1[hL];
    half_t* ph = p1s + (size_t)hL * N_EDGES;
    int jb = rowptr[w], je = rowptr[w + 1];
    for (int base = jb; base < je; base += 8) {
        int idx = base + eL;
        bool valid = idx < je;
        int2 ed = edges[valid ? idx : jb];
        float l = lrelu(s1[ed.x * NH1 + hL] + d1L + __int_as_float(ed.y) * aeL);
        if (valid) ph[idx] = (half_t)__expf(l);
    }
}

// ---- K_node1: wave per dst node, lane = hA*8+f. 8-wide aligned chunks:
//      4 int4 edge loads + 1 16-B p1 load + 8 independent H1 gathers.
//      Scalar pre/tail loops reach 8-alignment. Fused elu+GEMM2+s2/d2. ----
__global__ __launch_bounds__(256) void k_node1(
    const int* __restrict__ rowptr, const int2* __restrict__ edges,
    const half_t* __restrict__ p1s, const ushort_t* __restrict__ H1,
    const float* __restrict__ W2, const float* __restrict__ as2,
    const float* __restrict__ ad2,
    ushort_t* __restrict__ H2, float* __restrict__ s2, float* __restrict__ d2)
{
    int w = (blockIdx.x * blockDim.x + threadIdx.x) >> 6;
    int lane = threadIdx.x & 63;
    if (w >= N_NODES) return;
    int hA = lane >> 3;
    const half_t* ph = p1s + (size_t)hA * N_EDGES;
    int jb = rowptr[w], je = rowptr[w + 1];
    float dn0 = 0.f, dn1 = 0.f, dn2 = 0.f, dn3 = 0.f;
    float dn4 = 0.f, dn5 = 0.f, dn6 = 0.f, dn7 = 0.f;
    float ac0 = 0.f, ac1 = 0.f, ac2 = 0.f, ac3 = 0.f;
    float ac4 = 0.f, ac5 = 0.f, ac6 = 0.f, ac7 = 0.f;
    int j = jb;
    int jA = (jb + 7) & ~7;
    for (; j < je && j < jA; ++j) {          // pre-loop to alignment
        float p0 = (float)ph[j];
        dn0 += p0;
        ac0 = fmaf(p0, bf2f(H1[(size_t)edges[j].x * C1 + lane]), ac0);
    }
    for (; j + 8 <= je; j += 8) {            // aligned 8-chunks
        int4 e01 = *(const int4*)&edges[j];
        int4 e23 = *(const int4*)&edges[j + 2];
        int4 e45 = *(const int4*)&edges[j + 4];
        int4 e67 = *(const int4*)&edges[j + 6];
        half8 pv = *(const half8*)&ph[j];
        float h0 = bf2f(H1[(size_t)e01.x * C1 + lane]);
        float h1 = bf2f(H1[(size_t)e01.z * C1 + lane]);
        float h2_ = bf2f(H1[(size_t)e23.x * C1 + lane]);
        float h3 = bf2f(H1[(size_t)e23.z * C1 + lane]);
        float h4 = bf2f(H1[(size_t)e45.x * C1 + lane]);
        float h5 = bf2f(H1[(size_t)e45.z * C1 + lane]);
        float h6 = bf2f(H1[(size_t)e67.x * C1 + lane]);
        float h7 = bf2f(H1[(size_t)e67.z * C1 + lane]);
        float p0 = (float)pv[0], p1v = (float)pv[1], p2v = (float)pv[2], p3 = (float)pv[3];
        float p4 = (float)pv[4], p5 = (float)pv[5], p6 = (float)pv[6], p7 = (float)pv[7];
        dn0 += p0; dn1 += p1v; dn2 += p2v; dn3 += p3;
        dn4 += p4; dn5 += p5; dn6 += p6; dn7 += p7;
        ac0 = fmaf(p0, h0, ac0); ac1 = fmaf(p1v, h1, ac1);
        ac2 = fmaf(p2v, h2_, ac2); ac3 = fmaf(p3, h3, ac3);
        ac4 = fmaf(p4, h4, ac4); ac5 = fmaf(p5, h5, ac5);
        ac6 = fmaf(p6, h6, ac6); ac7 = fmaf(p7, h7, ac7);
    }
    for (; j < je; ++j) {                    // tail
        float p0 = (float)ph[j];
        dn0 += p0;
        ac0 = fmaf(p0, bf2f(H1[(size_t)edges[j].x * C1 + lane]), ac0);
    }
    float den = ((dn0 + dn1) + (dn2 + dn3)) + ((dn4 + dn5) + (dn6 + dn7));
    float acc = ((ac0 + ac1) + (ac2 + ac3)) + ((ac4 + ac5) + (ac6 + ac7));
    float o = acc / (den + 1e-16f);
    float r = o > 0.f ? o : __expf(o) - 1.f;   // elu
    int c = lane < C2 ? lane : 0;
    float h2 = 0.f;
    #pragma unroll 8
    for (int k = 0; k < C1; ++k) {
        float rk = __shfl(r, k);
        h2 = fmaf(rk, W2[k * C2 + c], h2);
    }
    float ps = lane < C2 ? h2 * as2[c] : 0.f;
    float pd = lane < C2 ? h2 * ad2[c] : 0.f;
    #pragma unroll
    for (int off = 32; off; off >>= 1) {
        ps += __shfl_xor(ps, off);
        pd += __shfl_xor(pd, off);
    }
    if (lane < C2) H2[(size_t)w * C1 + lane] = f2bf(h2);  // stride 64 (padded)
    if (lane == 0) { s2[w] = ps; d2[w] = pd; }
}

// ---- K_logit2: wave per dst node, lane = edge offset. p2[pos] fp16. ----
__global__ __launch_bounds__(256) void k_logit2(
    const int* __restrict__ rowptr, const int2* __restrict__ edges,
    const float* __restrict__ s2, const float* __restrict__ d2,
    const float* __restrict__ ae2, half_t* __restrict__ p2)
{
    int w = (blockIdx.x * blockDim.x + threadIdx.x) >> 6;
    int lane = threadIdx.x & 63;
    if (w >= N_NODES) return;
    float d2v = d2[w];
    float aev = ae2[0];
    int jb = rowptr[w], je = rowptr[w + 1];
    for (int idx = jb + lane; idx < je; idx += 64) {
        int2 ed = edges[idx];
        float l = lrelu(s2[ed.x] + d2v + __int_as_float(ed.y) * aev);
        p2[idx] = (half_t)__expf(l);
    }
}

// ---- K_node2: wave per dst node, lane = class. 8-wide aligned chunks,
//      8 independent H2 gathers. Fused log_softmax. ----
__global__ __launch_bounds__(256) void k_node2(
    const int* __restrict__ rowptr, const int2* __restrict__ edges,
    const half_t* __restrict__ p2, const ushort_t* __restrict__ H2,
    float* __restrict__ out)
{
    int w = (blockIdx.x * blockDim.x + threadIdx.x) >> 6;
    int lane = threadIdx.x & 63;
    if (w >= N_NODES) return;
    int c = lane < C2 ? lane : 0;
    int jb = rowptr[w], je = rowptr[w + 1];
    float dn0 = 0.f, dn1 = 0.f, dn2 = 0.f, dn3 = 0.f;
    float dn4 = 0.f, dn5 = 0.f, dn6 = 0.f, dn7 = 0.f;
    float ac0 = 0.f, ac1 = 0.f, ac2 = 0.f, ac3 = 0.f;
    float ac4 = 0.f, ac5 = 0.f, ac6 = 0.f, ac7 = 0.f;
    int j = jb;
    int jA = (jb + 7) & ~7;
    for (; j < je && j < jA; ++j) {
        float p0 = (float)p2[j];
        dn0 += p0;
        ac0 = fmaf(p0, bf2f(H2[(size_t)edges[j].x * C1 + c]), ac0);
    }
    for (; j + 8 <= je; j += 8) {
        int4 e01 = *(const int4*)&edges[j];
        int4 e23 = *(const int4*)&edges[j + 2];
        int4 e45 = *(const int4*)&edges[j + 4];
        int4 e67 = *(const int4*)&edges[j + 6];
        half8 pv = *(const half8*)&p2[j];
        float h0 = bf2f(H2[(size_t)e01.x * C1 + c]);
        float h1 = bf2f(H2[(size_t)e01.z * C1 + c]);
        float h2_ = bf2f(H2[(size_t)e23.x * C1 + c]);
        float h3 = bf2f(H2[(size_t)e23.z * C1 + c]);
        float h4 = bf2f(H2[(size_t)e45.x * C1 + c]);
        float h5 = bf2f(H2[(size_t)e45.z * C1 + c]);
        float h6 = bf2f(H2[(size_t)e67.x * C1 + c]);
        float h7 = bf2f(H2[(size_t)e67.z * C1 + c]);
        float p0 = (float)pv[0], p1v = (float)pv[1], p2v = (float)pv[2], p3 = (float)pv[3];
        float p4 = (float)pv[4], p5 = (float)pv[5], p6 = (float)pv[6], p7 = (float)pv[7];
        dn0 += p0; dn1 += p1v; dn2 += p2v; dn3 += p3;
        dn4 += p4; dn5 += p5; dn6 += p6; dn7 += p7;
        ac0 = fmaf(p0, h0, ac0); ac1 = fmaf(p1v, h1, ac1);
        ac2 = fmaf(p2v, h2_, ac2); ac3 = fmaf(p3, h3, ac3);
        ac4 = fmaf(p4, h4, ac4); ac5 = fmaf(p5, h5, ac5);
        ac6 = fmaf(p6, h6, ac6); ac7 = fmaf(p7, h7, ac7);
    }
    for (; j < je; ++j) {
        float p0 = (float)p2[j];
        dn0 += p0;
        ac0 = fmaf(p0, bf2f(H2[(size_t)edges[j].x * C1 + c]), ac0);
    }
    float den = ((dn0 + dn1) + (dn2 + dn3)) + ((dn4 + dn5) + (dn6 + dn7));
    float acc = ((ac0 + ac1) + (ac2 + ac3)) + ((ac4 + ac5) + (ac6 + ac7));
    float o = acc / (den + 1e-16f);
    float v = lane < C2 ? o : -INFINITY;
    float m = v;
    #pragma unroll
    for (int off = 32; off; off >>= 1) m = fmaxf(m, __shfl_xor(m, off));
    float p = lane < C2 ? __expf(v - m) : 0.f;
    #pragma unroll
    for (int off = 32; off; off >>= 1) p += __shfl_xor(p, off);
    float ls = __logf(p);
    if (lane < C2) out[(size_t)w * C2 + lane] = v - m - ls;
}

extern "C" void kernel_launch(void* const* d_in, const int* in_sizes, int n_in,
                              void* d_out, int out_size, void* d_ws, size_t ws_size,
                              hipStream_t stream)
{
    const float* x   = (const float*)d_in[0];
    const int*   ei  = (const int*)  d_in[1];
    const float* ea  = (const float*)d_in[2];
    const float* W1  = (const float*)d_in[3];
    const float* as1 = (const float*)d_in[4];
    const float* ad1 = (const float*)d_in[5];
    const float* ae1 = (const float*)d_in[6];
    const float* W2  = (const float*)d_in[7];
    const float* as2 = (const float*)d_in[8];
    const float* ad2 = (const float*)d_in[9];
    const float* ae2 = (const float*)d_in[10];
    float* out = (float*)d_out;

    // workspace layout (4-byte units), aliased to stay <= 72 MB.
    // rowptr needs 100,001 ints — s2 starts 8 words later (R5 overlap bug).
    // deg/rank/bsum/boff alias p1s (all dead before k_logit1 writes p1s).
    // p2 aliases s1 (s1 dead after k_logit1).
    float*    ws     = (float*)d_ws;
    ushort_t* H1     = (ushort_t*)ws;                 // [0, 3.2M)  6.4M bf16
    ushort_t* H2     = (ushort_t*)(ws + 3200000);     // [3.2M, 6.4M) stride-64 bf16
    int2*     edges  = (int2*)(ws + 6400000);         // [6.4M, 9.6M) 1.6M int2
    half_t*   p1s    = (half_t*)(ws + 9600000);       // [9.6M, 16.0M) SoA [8][E] fp16
    int*      deg    = (int*)(ws + 9600000);          //   alias
    int*      rank   = (int*)(ws + 9700000);          //   alias (1.6M ints)
    int*      bsum   = (int*)(ws + 11300000);         //   alias (391)
    int*      boff   = (int*)(ws + 11301000);         //   alias (391)
    float*    s1     = ws + 16000000;                 // [16.0M, 16.8M)
    half_t*   p2     = (half_t*)(ws + 16000000);      //   alias
    float*    d1     = ws + 16800000;                 // [16.8M, 17.6M)
    int*      rowptr = (int*)(ws + 17600000);         // 100,001 ints
    float*    s2     = ws + 17700008;                 // 100,000
    float*    d2     = ws + 17800008;                 // 100,000

    hipMemsetAsync(deg, 0, 100000 * 4, stream);

    k_gemm1     <<<N_NODES / 4, 256, 0, stream>>>(x, W1, as1, ad1, H1, s1, d1);
    k_count     <<<(N_EDGES + 255) / 256, 256, 0, stream>>>(ei, deg, rank);
    k_red       <<<N_SBLK, SCAN_B, 0, stream>>>(deg, bsum);
    k_scan_small<<<1, 512, 0, stream>>>(bsum, boff, rowptr);
    k_apply     <<<N_SBLK, SCAN_B, 0, stream>>>(deg, boff, rowptr);
    k_fill      <<<(N_EDGES + 255) / 256, 256, 0, stream>>>(ei, ea, rowptr, rank, edges);
    k_logit1    <<<(N_NODES + 3) / 4, 256, 0, stream>>>(rowptr, edges, s1, d1, ae1, p1s);
    k_node1     <<<(N_NODES + 3) / 4, 256, 0, stream>>>(rowptr, edges, p1s, H1,
                                                        W2, as2, ad2, H2, s2, d2);
    k_logit2    <<<(N_NODES + 3) / 4, 256, 0, stream>>>(rowptr, edges, s2, d2, ae2, p2);
    k_node2     <<<(N_NODES + 3) / 4, 256, 0, stream>>>(rowptr, edges, p2, H2, out);
}

// Round 10
// 519.526 us; speedup vs baseline: 1.1517x; 1.1517x over previous
//
#include <hip/hip_runtime.h>
#include <math.h>

#define N_NODES 100000
#define N_EDGES 1600000
#define IN_F    128
#define NH1     8
#define HID     8
#define C1      64   // NH1*HID
#define C2      40   // N_CLASSES
#define SCAN_B  256
#define N_SBLK  ((N_NODES + SCAN_B - 1) / SCAN_B)   // 391

typedef unsigned short ushort_t;
typedef unsigned int uint_t;
typedef _Float16 half_t;
typedef short short8 __attribute__((ext_vector_type(8)));
typedef float f32x4 __attribute__((ext_vector_type(4)));

__device__ __forceinline__ float lrelu(float x) { return x > 0.f ? x : 0.2f * x; }
__device__ __forceinline__ ushort_t f2bf(float f) {
    uint_t u = __float_as_uint(f);
    u = (u + 0x7FFFu + ((u >> 16) & 1u)) >> 16;   // round-to-nearest-even
    return (ushort_t)u;
}
__device__ __forceinline__ float bf2f(ushort_t s) {
    return __uint_as_float(((uint_t)s) << 16);
}

// ---- K1: H1(bf16) = x@W1 ; s1[n,h], d1[n,h] attention dots. 4 nodes/block ----
__global__ __launch_bounds__(256) void k_gemm1(
    const float* __restrict__ x, const float* __restrict__ W1,
    const float* __restrict__ as1, const float* __restrict__ ad1,
    ushort_t* __restrict__ H1, float* __restrict__ s1, float* __restrict__ d1)
{
    __shared__ float xs[4][IN_F];
    int wv = threadIdx.x >> 6, lane = threadIdx.x & 63;
    int n = blockIdx.x * 4 + wv;
    ((float2*)xs[wv])[lane] = ((const float2*)(x + (size_t)n * IN_F))[lane];
    __syncthreads();
    float acc = 0.f;
    #pragma unroll
    for (int k = 0; k < IN_F; k += 4) {
        float4 xk = *(const float4*)&xs[wv][k];
        acc = fmaf(xk.x, W1[(k + 0) * C1 + lane], acc);
        acc = fmaf(xk.y, W1[(k + 1) * C1 + lane], acc);
        acc = fmaf(xk.z, W1[(k + 2) * C1 + lane], acc);
        acc = fmaf(xk.w, W1[(k + 3) * C1 + lane], acc);
    }
    H1[(size_t)n * C1 + lane] = f2bf(acc);
    float ps = acc * as1[lane], pd = acc * ad1[lane];  // lane == h*8+f
    #pragma unroll
    for (int off = 4; off; off >>= 1) {
        ps += __shfl_xor(ps, off);
        pd += __shfl_xor(pd, off);
    }
    if ((lane & 7) == 0) {
        s1[n * NH1 + (lane >> 3)] = ps;
        d1[n * NH1 + (lane >> 3)] = pd;
    }
}

// ---- W2 pre-swizzle: bf16 B-fragments for mfma_f32_16x16x32_bf16.
//      W2p[((nt*2+khalf)*64 + lane)*8 + j] = W2[k][n], n=nt*16+(lane&15),
//      k=khalf*32+(lane>>4)*8+j, zero-padded for n>=40. 3072 elems. ----
__global__ __launch_bounds__(256) void k_w2prep(
    const float* __restrict__ W2, ushort_t* __restrict__ W2p)
{
    int i = blockIdx.x * 256 + threadIdx.x;
    if (i >= 3072) return;
    int j = i & 7, lane = (i >> 3) & 63, khalf = (i >> 9) & 1, nt = i >> 10;
    int n = nt * 16 + (lane & 15);
    int k = khalf * 32 + (lane >> 4) * 8 + j;
    float v = (n < C2) ? W2[k * C2 + n] : 0.f;
    W2p[i] = f2bf(v);
}

// ---- CSR build: degree count + per-edge rank (old value of the counter) ----
__global__ __launch_bounds__(256) void k_count(
    const int* __restrict__ ei, int* __restrict__ deg, int* __restrict__ rank)
{
    int e = blockIdx.x * blockDim.x + threadIdx.x;
    if (e >= N_EDGES) return;
    rank[e] = atomicAdd(&deg[ei[N_EDGES + e]], 1);
}

// ---- scan phase 1: per-block (256-wide) reduction of deg -> bsum ----
__global__ __launch_bounds__(SCAN_B) void k_red(
    const int* __restrict__ deg, int* __restrict__ bsum)
{
    int t = threadIdx.x, lane = t & 63, wv = t >> 6;
    int i = blockIdx.x * SCAN_B + t;
    int v = (i < N_NODES) ? deg[i] : 0;
    #pragma unroll
    for (int off = 32; off; off >>= 1) v += __shfl_xor(v, off);
    __shared__ int s[4];
    if (lane == 0) s[wv] = v;
    __syncthreads();
    if (t == 0) bsum[blockIdx.x] = s[0] + s[1] + s[2] + s[3];
}

// ---- scan phase 2: single small block scans the 391 block sums ----
__global__ __launch_bounds__(512) void k_scan_small(
    const int* __restrict__ bsum, int* __restrict__ boff,
    int* __restrict__ rowptr)
{
    __shared__ int s[512];
    int t = threadIdx.x;
    int v = (t < N_SBLK) ? bsum[t] : 0;
    s[t] = v;
    __syncthreads();
    for (int off = 1; off < 512; off <<= 1) {
        int u = (t >= off) ? s[t - off] : 0;
        __syncthreads();
        s[t] += u;
        __syncthreads();
    }
    if (t < N_SBLK) boff[t] = s[t] - v;          // exclusive
    if (t == 511) rowptr[N_NODES] = s[511];      // total == N_EDGES
}

// ---- scan phase 3: in-block exclusive scan + block offset -> rowptr ----
__global__ __launch_bounds__(SCAN_B) void k_apply(
    const int* __restrict__ deg, const int* __restrict__ boff,
    int* __restrict__ rowptr)
{
    int t = threadIdx.x, lane = t & 63, wv = t >> 6;
    int i = blockIdx.x * SCAN_B + t;
    int v = (i < N_NODES) ? deg[i] : 0;
    int inc = v;
    #pragma unroll
    for (int off = 1; off < 64; off <<= 1) {
        int u = __shfl_up(inc, off);
        if (lane >= off) inc += u;
    }
    __shared__ int ws_[4];
    if (lane == 63) ws_[wv] = inc;
    __syncthreads();
    int add = 0;
    for (int k = 0; k < wv; k++) add += ws_[k];
    if (i < N_NODES) rowptr[i] = inc - v + add + boff[blockIdx.x];
}

// ---- CSR build: fill packed (src, w) — NO atomics, one 8-B store/edge ----
__global__ __launch_bounds__(256) void k_fill(
    const int* __restrict__ ei, const float* __restrict__ ea,
    const int* __restrict__ rowptr, const int* __restrict__ rank,
    int2* __restrict__ edges)
{
    int e = blockIdx.x * blockDim.x + threadIdx.x;
    if (e >= N_EDGES) return;
    int s = ei[e], d = ei[N_EDGES + e];
    int pos = rowptr[d] + rank[e];
    edges[pos] = make_int2(s, __float_as_int(ea[e]));
}

// ---- K_logit1: wave per dst node, lane = eL*8 + hL. p1 AoS [E][8] fp16
//      (R8 lesson: SoA spreads a node's p-reads over 8 streams -> +fetch). ----
__global__ __launch_bounds__(256) void k_logit1(
    const int* __restrict__ rowptr, const int2* __restrict__ edges,
    const float* __restrict__ s1, const float* __restrict__ d1,
    const float* __restrict__ ae1, half_t* __restrict__ p1)
{
    int w = (blockIdx.x * blockDim.x + threadIdx.x) >> 6;
    int lane = threadIdx.x & 63;
    if (w >= N_NODES) return;
    int hL = lane & 7, eL = lane >> 3;
    float d1L = d1[w * NH1 + hL];
    float aeL = ae1[hL];
    int jb = rowptr[w], je = rowptr[w + 1];
    for (int base = jb; base < je; base += 8) {
        int idx = base + eL;
        bool valid = idx < je;
        int2 ed = edges[valid ? idx : jb];
        float l = lrelu(s1[ed.x * NH1 + hL] + d1L + __int_as_float(ed.y) * aeL);
        if (valid) p1[(size_t)idx * NH1 + hL] = (half_t)__expf(l);
    }
}

// ---- K_node1: wave per dst node, lane = hA*8+f. R7 lean loop (4-unroll,
//      AoS p1). Epilogue now just elu + bf16 store of r (GEMM2 moved to
//      MFMA kernel). ----
__global__ __launch_bounds__(256) void k_node1(
    const int* __restrict__ rowptr, const int2* __restrict__ edges,
    const half_t* __restrict__ p1, const ushort_t* __restrict__ H1,
    ushort_t* __restrict__ out1r)
{
    int w = (blockIdx.x * blockDim.x + threadIdx.x) >> 6;
    int lane = threadIdx.x & 63;
    if (w >= N_NODES) return;
    int hA = lane >> 3;
    int jb = rowptr[w], je = rowptr[w + 1];
    float den0 = 0.f, den1 = 0.f, den2_ = 0.f, den3 = 0.f;
    float acc0 = 0.f, acc1 = 0.f, acc2 = 0.f, acc3 = 0.f;
    int j = jb;
    for (; j + 3 < je; j += 4) {
        int s0 = edges[j].x, s1_ = edges[j + 1].x;
        int s2_ = edges[j + 2].x, s3 = edges[j + 3].x;
        float p0 = (float)p1[(size_t)(j + 0) * NH1 + hA];
        float p1v = (float)p1[(size_t)(j + 1) * NH1 + hA];
        float p2v = (float)p1[(size_t)(j + 2) * NH1 + hA];
        float p3 = (float)p1[(size_t)(j + 3) * NH1 + hA];
        float h0 = bf2f(H1[(size_t)s0 * C1 + lane]);
        float h1 = bf2f(H1[(size_t)s1_ * C1 + lane]);
        float h2_ = bf2f(H1[(size_t)s2_ * C1 + lane]);
        float h3 = bf2f(H1[(size_t)s3 * C1 + lane]);
        den0 += p0; den1 += p1v; den2_ += p2v; den3 += p3;
        acc0 = fmaf(p0, h0, acc0);
        acc1 = fmaf(p1v, h1, acc1);
        acc2 = fmaf(p2v, h2_, acc2);
        acc3 = fmaf(p3, h3, acc3);
    }
    for (; j < je; ++j) {
        int s0 = edges[j].x;
        float p0 = (float)p1[(size_t)j * NH1 + hA];
        den0 += p0;
        acc0 = fmaf(p0, bf2f(H1[(size_t)s0 * C1 + lane]), acc0);
    }
    float den = (den0 + den1) + (den2_ + den3);
    float acc = (acc0 + acc1) + (acc2 + acc3);
    float o = acc / (den + 1e-16f);
    float r = o > 0.f ? o : __expf(o) - 1.f;   // elu
    out1r[(size_t)w * C1 + lane] = f2bf(r);
}

// ---- K_gemm2 (MFMA): H2[100k x 40] = out1r[100k x 64] @ W2 (bf16), plus
//      s2/d2 dots. Wave per 16-node tile: 2 K-halves x 3 N-tiles = 6 MFMAs.
//      A: lane holds A[m=lane&15][k=quad*8+j]; B pre-swizzled (k_w2prep);
//      C/D: col=lane&15, row=quad*4+reg (verified layout). ----
__global__ __launch_bounds__(256) void k_gemm2(
    const ushort_t* __restrict__ out1r, const ushort_t* __restrict__ W2p,
    const float* __restrict__ as2, const float* __restrict__ ad2,
    ushort_t* __restrict__ H2, float* __restrict__ s2, float* __restrict__ d2)
{
    int tile = (blockIdx.x * blockDim.x + threadIdx.x) >> 6;
    int lane = threadIdx.x & 63;
    if (tile >= N_NODES / 16) return;
    int quad = lane >> 4, lo = lane & 15;
    const ushort_t* arow = out1r + ((size_t)tile * 16 + lo) * C1 + quad * 8;
    short8 a0 = *(const short8*)arow;          // k = quad*8+j
    short8 a1 = *(const short8*)(arow + 32);   // k = 32+quad*8+j
    f32x4 acc[3] = {{0,0,0,0},{0,0,0,0},{0,0,0,0}};
    #pragma unroll
    for (int nt = 0; nt < 3; ++nt) {
        short8 b0 = *(const short8*)&W2p[((nt * 2 + 0) * 64 + lane) * 8];
        short8 b1 = *(const short8*)&W2p[((nt * 2 + 1) * 64 + lane) * 8];
        acc[nt] = __builtin_amdgcn_mfma_f32_16x16x32_bf16(a0, b0, acc[nt], 0, 0, 0);
        acc[nt] = __builtin_amdgcn_mfma_f32_16x16x32_bf16(a1, b1, acc[nt], 0, 0, 0);
    }
    float ps0 = 0.f, ps1 = 0.f, ps2 = 0.f, ps3 = 0.f;
    float pd0 = 0.f, pd1 = 0.f, pd2 = 0.f, pd3 = 0.f;
    #pragma unroll
    for (int nt = 0; nt < 3; ++nt) {
        int cb = nt * 16 + lo;
        float a2 = cb < C2 ? as2[cb] : 0.f;
        float b2 = cb < C2 ? ad2[cb] : 0.f;
        float v0 = acc[nt][0], v1 = acc[nt][1], v2 = acc[nt][2], v3 = acc[nt][3];
        int nb = tile * 16 + quad * 4;
        H2[(size_t)(nb + 0) * C1 + cb] = f2bf(v0);
        H2[(size_t)(nb + 1) * C1 + cb] = f2bf(v1);
        H2[(size_t)(nb + 2) * C1 + cb] = f2bf(v2);
        H2[(size_t)(nb + 3) * C1 + cb] = f2bf(v3);
        ps0 = fmaf(v0, a2, ps0); ps1 = fmaf(v1, a2, ps1);
        ps2 = fmaf(v2, a2, ps2); ps3 = fmaf(v3, a2, ps3);
        pd0 = fmaf(v0, b2, pd0); pd1 = fmaf(v1, b2, pd1);
        pd2 = fmaf(v2, b2, pd2); pd3 = fmaf(v3, b2, pd3);
    }
    #pragma unroll
    for (int off = 1; off < 16; off <<= 1) {
        ps0 += __shfl_xor(ps0, off); ps1 += __shfl_xor(ps1, off);
        ps2 += __shfl_xor(ps2, off); ps3 += __shfl_xor(ps3, off);
        pd0 += __shfl_xor(pd0, off); pd1 += __shfl_xor(pd1, off);
        pd2 += __shfl_xor(pd2, off); pd3 += __shfl_xor(pd3, off);
    }
    if (lo == 0) {
        int nb = tile * 16 + quad * 4;
        s2[nb + 0] = ps0; s2[nb + 1] = ps1; s2[nb + 2] = ps2; s2[nb + 3] = ps3;
        d2[nb + 0] = pd0; d2[nb + 1] = pd1; d2[nb + 2] = pd2; d2[nb + 3] = pd3;
    }
}

// ---- K_logit2: wave per dst node, lane = edge offset. p2[pos] fp16. ----
__global__ __launch_bounds__(256) void k_logit2(
    const int* __restrict__ rowptr, const int2* __restrict__ edges,
    const float* __restrict__ s2, const float* __restrict__ d2,
    const float* __restrict__ ae2, half_t* __restrict__ p2)
{
    int w = (blockIdx.x * blockDim.x + threadIdx.x) >> 6;
    int lane = threadIdx.x & 63;
    if (w >= N_NODES) return;
    float d2v = d2[w];
    float aev = ae2[0];
    int jb = rowptr[w], je = rowptr[w + 1];
    for (int idx = jb + lane; idx < je; idx += 64) {
        int2 ed = edges[idx];
        float l = lrelu(s2[ed.x] + d2v + __int_as_float(ed.y) * aev);
        p2[idx] = (half_t)__expf(l);
    }
}

// ---- K_node2: wave per dst node, lane = class. R7 lean 4-unroll loop.
//      Fused log_softmax. ----
__global__ __launch_bounds__(256) void k_node2(
    const int* __restrict__ rowptr, const int2* __restrict__ edges,
    const half_t* __restrict__ p2, const ushort_t* __restrict__ H2,
    float* __restrict__ out)
{
    int w = (blockIdx.x * blockDim.x + threadIdx.x) >> 6;
    int lane = threadIdx.x & 63;
    if (w >= N_NODES) return;
    int c = lane < C2 ? lane : 0;
    int jb = rowptr[w], je = rowptr[w + 1];
    float den0 = 0.f, den1 = 0.f, den2_ = 0.f, den3 = 0.f;
    float acc0 = 0.f, acc1 = 0.f, acc2 = 0.f, acc3 = 0.f;
    int j = jb;
    for (; j + 3 < je; j += 4) {
        int s0 = edges[j].x, s1_ = edges[j + 1].x;
        int s2_ = edges[j + 2].x, s3 = edges[j + 3].x;
        float p0 = (float)p2[j], p1v = (float)p2[j + 1];
        float p2v = (float)p2[j + 2], p3 = (float)p2[j + 3];
        float h0 = bf2f(H2[(size_t)s0 * C1 + c]);
        float h1 = bf2f(H2[(size_t)s1_ * C1 + c]);
        float h2_ = bf2f(H2[(size_t)s2_ * C1 + c]);
        float h3 = bf2f(H2[(size_t)s3 * C1 + c]);
        den0 += p0; den1 += p1v; den2_ += p2v; den3 += p3;
        acc0 = fmaf(p0, h0, acc0);
        acc1 = fmaf(p1v, h1, acc1);
        acc2 = fmaf(p2v, h2_, acc2);
        acc3 = fmaf(p3, h3, acc3);
    }
    for (; j < je; ++j) {
        int s0 = edges[j].x;
        float p0 = (float)p2[j];
        den0 += p0;
        acc0 = fmaf(p0, bf2f(H2[(size_t)s0 * C1 + c]), acc0);
    }
    float den = (den0 + den1) + (den2_ + den3);
    float acc = (acc0 + acc1) + (acc2 + acc3);
    float o = acc / (den + 1e-16f);
    float v = lane < C2 ? o : -INFINITY;
    float m = v;
    #pragma unroll
    for (int off = 32; off; off >>= 1) m = fmaxf(m, __shfl_xor(m, off));
    float p = lane < C2 ? __expf(v - m) : 0.f;
    #pragma unroll
    for (int off = 32; off; off >>= 1) p += __shfl_xor(p, off);
    float ls = __logf(p);
    if (lane < C2) out[(size_t)w * C2 + lane] = v - m - ls;
}

extern "C" void kernel_launch(void* const* d_in, const int* in_sizes, int n_in,
                              void* d_out, int out_size, void* d_ws, size_t ws_size,
                              hipStream_t stream)
{
    const float* x   = (const float*)d_in[0];
    const int*   ei  = (const int*)  d_in[1];
    const float* ea  = (const float*)d_in[2];
    const float* W1  = (const float*)d_in[3];
    const float* as1 = (const float*)d_in[4];
    const float* ad1 = (const float*)d_in[5];
    const float* ae1 = (const float*)d_in[6];
    const float* W2  = (const float*)d_in[7];
    const float* as2 = (const float*)d_in[8];
    const float* ad2 = (const float*)d_in[9];
    const float* ae2 = (const float*)d_in[10];
    float* out = (float*)d_out;

    // workspace layout (4-byte units), aliased to stay <= 72 MB:
    //   H1 [0,3.2M) dead after k_node1 -> reused as H2 (written by k_gemm2)
    //   out1r takes H2's old slot [3.2M,6.4M)
    //   deg/rank/bsum/boff alias p1 (dead before k_logit1 writes p1)
    //   p2 aliases s1 (s1 dead after k_logit1)
    //   rowptr needs 100,001 ints -> s2 starts 8 words later (R5 lesson)
    float*    ws     = (float*)d_ws;
    ushort_t* H1     = (ushort_t*)ws;                 // [0, 3.2M)  bf16
    ushort_t* H2     = (ushort_t*)ws;                 //   alias (after node1)
    ushort_t* out1r  = (ushort_t*)(ws + 3200000);     // [3.2M, 6.4M) bf16 r rows
    int2*     edges  = (int2*)(ws + 6400000);         // [6.4M, 9.6M) 1.6M int2
    half_t*   p1     = (half_t*)(ws + 9600000);       // [9.6M, 16.0M) AoS [E][8]
    int*      deg    = (int*)(ws + 9600000);          //   alias
    int*      rank   = (int*)(ws + 9700000);          //   alias (1.6M ints)
    int*      bsum   = (int*)(ws + 11300000);         //   alias (391)
    int*      boff   = (int*)(ws + 11301000);         //   alias (391)
    float*    s1     = ws + 16000000;                 // [16.0M, 16.8M)
    half_t*   p2     = (half_t*)(ws + 16000000);      //   alias
    float*    d1     = ws + 16800000;                 // [16.8M, 17.6M)
    int*      rowptr = (int*)(ws + 17600000);         // 100,001 ints
    float*    s2     = ws + 17700008;                 // 100,000
    float*    d2     = ws + 17800008;                 // 100,000
    ushort_t* W2p    = (ushort_t*)(ws + 17900008);    // 3072 bf16 (1536 words)

    hipMemsetAsync(deg, 0, 100000 * 4, stream);

    k_gemm1     <<<N_NODES / 4, 256, 0, stream>>>(x, W1, as1, ad1, H1, s1, d1);
    k_w2prep    <<<12, 256, 0, stream>>>(W2, W2p);
    k_count     <<<(N_EDGES + 255) / 256, 256, 0, stream>>>(ei, deg, rank);
    k_red       <<<N_SBLK, SCAN_B, 0, stream>>>(deg, bsum);
    k_scan_small<<<1, 512, 0, stream>>>(bsum, boff, rowptr);
    k_apply     <<<N_SBLK, SCAN_B, 0, stream>>>(deg, boff, rowptr);
    k_fill      <<<(N_EDGES + 255) / 256, 256, 0, stream>>>(ei, ea, rowptr, rank, edges);
    k_logit1    <<<(N_NODES + 3) / 4, 256, 0, stream>>>(rowptr, edges, s1, d1, ae1, p1);
    k_node1     <<<(N_NODES + 3) / 4, 256, 0, stream>>>(rowptr, edges, p1, H1, out1r);
    k_gemm2     <<<(N_NODES / 16 + 3) / 4, 256, 0, stream>>>(out1r, W2p, as2, ad2,
                                                             H2, s2, d2);
    k_logit2    <<<(N_NODES + 3) / 4, 256, 0, stream>>>(rowptr, edges, s2, d2, ae2, p2);
    k_node2     <<<(N_NODES + 3) / 4, 256, 0, stream>>>(rowptr, edges, p2, H2, out);
}

// Round 11
// 455.880 us; speedup vs baseline: 1.3125x; 1.1396x over previous
//
#include <hip/hip_runtime.h>
#include <math.h>

#define N_NODES 100000
#define N_EDGES 1600000
#define IN_F    128
#define NH1     8
#define HID     8
#define C1      64   // NH1*HID
#define C2      40   // N_CLASSES
#define SCAN_B  256
#define N_SBLK  ((N_NODES + SCAN_B - 1) / SCAN_B)   // 391

typedef unsigned short ushort_t;
typedef unsigned int uint_t;
typedef _Float16 half_t;
typedef short short8 __attribute__((ext_vector_type(8)));
typedef float f32x4 __attribute__((ext_vector_type(4)));

__device__ __forceinline__ float lrelu(float x) { return x > 0.f ? x : 0.2f * x; }
__device__ __forceinline__ ushort_t f2bf(float f) {
    uint_t u = __float_as_uint(f);
    u = (u + 0x7FFFu + ((u >> 16) & 1u)) >> 16;   // round-to-nearest-even
    return (ushort_t)u;
}
__device__ __forceinline__ float bf2f(ushort_t s) {
    return __uint_as_float(((uint_t)s) << 16);
}

// ---- x -> bf16 cast (streaming, 8 elems/thread) ----
__global__ __launch_bounds__(256) void k_xcast(
    const float* __restrict__ x, ushort_t* __restrict__ xb)
{
    size_t i8 = (size_t)(blockIdx.x * 256 + threadIdx.x) * 8;   // 12.8M total
    float4 a = *(const float4*)(x + i8);
    float4 b = *(const float4*)(x + i8 + 4);
    ushort_t o[8] = {f2bf(a.x), f2bf(a.y), f2bf(a.z), f2bf(a.w),
                     f2bf(b.x), f2bf(b.y), f2bf(b.z), f2bf(b.w)};
    *(int4*)(xb + i8) = *(const int4*)o;
}

// ---- W1 pre-swizzle: B-frags for mfma_f32_16x16x32_bf16.
//      W1p[((s*4+nt)*64+lane)*8+j] = W1[k=s*32+(lane>>4)*8+j][n=nt*16+(lane&15)] ----
__global__ __launch_bounds__(256) void k_w1prep(
    const float* __restrict__ W1, ushort_t* __restrict__ W1p)
{
    int i = blockIdx.x * 256 + threadIdx.x;     // 8192
    if (i >= 8192) return;
    int j = i & 7, lane = (i >> 3) & 63, nt = (i >> 9) & 3, s = i >> 11;
    int k = s * 32 + (lane >> 4) * 8 + j;
    int n = nt * 16 + (lane & 15);
    W1p[i] = f2bf(W1[k * C1 + n]);
}

// ---- GEMM1 (MFMA): H1[100k x 64] = xb[100k x 128] @ W1. Wave per
//      16-node tile: 4 K-steps x 4 N-tiles = 16 MFMAs. ----
__global__ __launch_bounds__(256) void k_gemm1_mfma(
    const ushort_t* __restrict__ xb, const ushort_t* __restrict__ W1p,
    ushort_t* __restrict__ H1)
{
    int tile = (blockIdx.x * blockDim.x + threadIdx.x) >> 6;
    int lane = threadIdx.x & 63;
    if (tile >= N_NODES / 16) return;
    int quad = lane >> 4, lo = lane & 15;
    const ushort_t* arow = xb + ((size_t)tile * 16 + lo) * IN_F + quad * 8;
    short8 a0 = *(const short8*)arow;            // k = 0*32 + quad*8+j
    short8 a1 = *(const short8*)(arow + 32);
    short8 a2 = *(const short8*)(arow + 64);
    short8 a3 = *(const short8*)(arow + 96);
    f32x4 acc[4] = {{0,0,0,0},{0,0,0,0},{0,0,0,0},{0,0,0,0}};
    #pragma unroll
    for (int nt = 0; nt < 4; ++nt) {
        short8 b0 = *(const short8*)&W1p[((0 * 4 + nt) * 64 + lane) * 8];
        short8 b1 = *(const short8*)&W1p[((1 * 4 + nt) * 64 + lane) * 8];
        short8 b2 = *(const short8*)&W1p[((2 * 4 + nt) * 64 + lane) * 8];
        short8 b3 = *(const short8*)&W1p[((3 * 4 + nt) * 64 + lane) * 8];
        acc[nt] = __builtin_amdgcn_mfma_f32_16x16x32_bf16(a0, b0, acc[nt], 0, 0, 0);
        acc[nt] = __builtin_amdgcn_mfma_f32_16x16x32_bf16(a1, b1, acc[nt], 0, 0, 0);
        acc[nt] = __builtin_amdgcn_mfma_f32_16x16x32_bf16(a2, b2, acc[nt], 0, 0, 0);
        acc[nt] = __builtin_amdgcn_mfma_f32_16x16x32_bf16(a3, b3, acc[nt], 0, 0, 0);
    }
    int nb = tile * 16 + quad * 4;               // C/D: col=lo, row=quad*4+reg
    #pragma unroll
    for (int nt = 0; nt < 4; ++nt) {
        int cb = nt * 16 + lo;
        #pragma unroll
        for (int r = 0; r < 4; ++r)
            H1[(size_t)(nb + r) * C1 + cb] = f2bf(acc[nt][r]);
    }
}

// ---- s1/d1 dots from H1: wave per node, lane = h*8+f ----
__global__ __launch_bounds__(256) void k_sd1(
    const ushort_t* __restrict__ H1,
    const float* __restrict__ as1, const float* __restrict__ ad1,
    float* __restrict__ s1, float* __restrict__ d1)
{
    int n = (blockIdx.x * blockDim.x + threadIdx.x) >> 6;
    int lane = threadIdx.x & 63;
    if (n >= N_NODES) return;
    float h = bf2f(H1[(size_t)n * C1 + lane]);
    float ps = h * as1[lane], pd = h * ad1[lane];
    #pragma unroll
    for (int off = 4; off; off >>= 1) {
        ps += __shfl_xor(ps, off);
        pd += __shfl_xor(pd, off);
    }
    if ((lane & 7) == 0) {
        s1[n * NH1 + (lane >> 3)] = ps;
        d1[n * NH1 + (lane >> 3)] = pd;
    }
}

// ---- W2 pre-swizzle (as R9, verified) ----
__global__ __launch_bounds__(256) void k_w2prep(
    const float* __restrict__ W2, ushort_t* __restrict__ W2p)
{
    int i = blockIdx.x * 256 + threadIdx.x;
    if (i >= 3072) return;
    int j = i & 7, lane = (i >> 3) & 63, khalf = (i >> 9) & 1, nt = i >> 10;
    int n = nt * 16 + (lane & 15);
    int k = khalf * 32 + (lane >> 4) * 8 + j;
    float v = (n < C2) ? W2[k * C2 + n] : 0.f;
    W2p[i] = f2bf(v);
}

// ---- CSR build: degree count + per-edge rank ----
__global__ __launch_bounds__(256) void k_count(
    const int* __restrict__ ei, int* __restrict__ deg, int* __restrict__ rank)
{
    int e = blockIdx.x * blockDim.x + threadIdx.x;
    if (e >= N_EDGES) return;
    rank[e] = atomicAdd(&deg[ei[N_EDGES + e]], 1);
}

// ---- scan phase 1 ----
__global__ __launch_bounds__(SCAN_B) void k_red(
    const int* __restrict__ deg, int* __restrict__ bsum)
{
    int t = threadIdx.x, lane = t & 63, wv = t >> 6;
    int i = blockIdx.x * SCAN_B + t;
    int v = (i < N_NODES) ? deg[i] : 0;
    #pragma unroll
    for (int off = 32; off; off >>= 1) v += __shfl_xor(v, off);
    __shared__ int s[4];
    if (lane == 0) s[wv] = v;
    __syncthreads();
    if (t == 0) bsum[blockIdx.x] = s[0] + s[1] + s[2] + s[3];
}

// ---- scan phase 2 ----
__global__ __launch_bounds__(512) void k_scan_small(
    const int* __restrict__ bsum, int* __restrict__ boff,
    int* __restrict__ rowptr)
{
    __shared__ int s[512];
    int t = threadIdx.x;
    int v = (t < N_SBLK) ? bsum[t] : 0;
    s[t] = v;
    __syncthreads();
    for (int off = 1; off < 512; off <<= 1) {
        int u = (t >= off) ? s[t - off] : 0;
        __syncthreads();
        s[t] += u;
        __syncthreads();
    }
    if (t < N_SBLK) boff[t] = s[t] - v;
    if (t == 511) rowptr[N_NODES] = s[511];
}

// ---- scan phase 3 ----
__global__ __launch_bounds__(SCAN_B) void k_apply(
    const int* __restrict__ deg, const int* __restrict__ boff,
    int* __restrict__ rowptr)
{
    int t = threadIdx.x, lane = t & 63, wv = t >> 6;
    int i = blockIdx.x * SCAN_B + t;
    int v = (i < N_NODES) ? deg[i] : 0;
    int inc = v;
    #pragma unroll
    for (int off = 1; off < 64; off <<= 1) {
        int u = __shfl_up(inc, off);
        if (lane >= off) inc += u;
    }
    __shared__ int ws_[4];
    if (lane == 63) ws_[wv] = inc;
    __syncthreads();
    int add = 0;
    for (int k = 0; k < wv; k++) add += ws_[k];
    if (i < N_NODES) rowptr[i] = inc - v + add + boff[blockIdx.x];
}

// ---- CSR fill: no atomics, one 8-B store/edge ----
__global__ __launch_bounds__(256) void k_fill(
    const int* __restrict__ ei, const float* __restrict__ ea,
    const int* __restrict__ rowptr, const int* __restrict__ rank,
    int2* __restrict__ edges)
{
    int e = blockIdx.x * blockDim.x + threadIdx.x;
    if (e >= N_EDGES) return;
    int s = ei[e], d = ei[N_EDGES + e];
    int pos = rowptr[d] + rank[e];
    edges[pos] = make_int2(s, __float_as_int(ea[e]));
}

// ---- K_logit1: p1 AoS [E][8] fp16 ----
__global__ __launch_bounds__(256) void k_logit1(
    const int* __restrict__ rowptr, const int2* __restrict__ edges,
    const float* __restrict__ s1, const float* __restrict__ d1,
    const float* __restrict__ ae1, half_t* __restrict__ p1)
{
    int w = (blockIdx.x * blockDim.x + threadIdx.x) >> 6;
    int lane = threadIdx.x & 63;
    if (w >= N_NODES) return;
    int hL = lane & 7, eL = lane >> 3;
    float d1L = d1[w * NH1 + hL];
    float aeL = ae1[hL];
    int jb = rowptr[w], je = rowptr[w + 1];
    for (int base = jb; base < je; base += 8) {
        int idx = base + eL;
        bool valid = idx < je;
        int2 ed = edges[valid ? idx : jb];
        float l = lrelu(s1[ed.x * NH1 + hL] + d1L + __int_as_float(ed.y) * aeL);
        if (valid) p1[(size_t)idx * NH1 + hL] = (half_t)__expf(l);
    }
}

// ---- K_node1: R7 lean 4-unroll loop; epilogue stores elu(o) bf16 ----
__global__ __launch_bounds__(256) void k_node1(
    const int* __restrict__ rowptr, const int2* __restrict__ edges,
    const half_t* __restrict__ p1, const ushort_t* __restrict__ H1,
    ushort_t* __restrict__ out1r)
{
    int w = (blockIdx.x * blockDim.x + threadIdx.x) >> 6;
    int lane = threadIdx.x & 63;
    if (w >= N_NODES) return;
    int hA = lane >> 3;
    int jb = rowptr[w], je = rowptr[w + 1];
    float den0 = 0.f, den1 = 0.f, den2_ = 0.f, den3 = 0.f;
    float acc0 = 0.f, acc1 = 0.f, acc2 = 0.f, acc3 = 0.f;
    int j = jb;
    for (; j + 3 < je; j += 4) {
        int s0 = edges[j].x, s1_ = edges[j + 1].x;
        int s2_ = edges[j + 2].x, s3 = edges[j + 3].x;
        float p0 = (float)p1[(size_t)(j + 0) * NH1 + hA];
        float p1v = (float)p1[(size_t)(j + 1) * NH1 + hA];
        float p2v = (float)p1[(size_t)(j + 2) * NH1 + hA];
        float p3 = (float)p1[(size_t)(j + 3) * NH1 + hA];
        float h0 = bf2f(H1[(size_t)s0 * C1 + lane]);
        float h1 = bf2f(H1[(size_t)s1_ * C1 + lane]);
        float h2_ = bf2f(H1[(size_t)s2_ * C1 + lane]);
        float h3 = bf2f(H1[(size_t)s3 * C1 + lane]);
        den0 += p0; den1 += p1v; den2_ += p2v; den3 += p3;
        acc0 = fmaf(p0, h0, acc0);
        acc1 = fmaf(p1v, h1, acc1);
        acc2 = fmaf(p2v, h2_, acc2);
        acc3 = fmaf(p3, h3, acc3);
    }
    for (; j < je; ++j) {
        int s0 = edges[j].x;
        float p0 = (float)p1[(size_t)j * NH1 + hA];
        den0 += p0;
        acc0 = fmaf(p0, bf2f(H1[(size_t)s0 * C1 + lane]), acc0);
    }
    float den = (den0 + den1) + (den2_ + den3);
    float acc = (acc0 + acc1) + (acc2 + acc3);
    float o = acc / (den + 1e-16f);
    float r = o > 0.f ? o : __expf(o) - 1.f;   // elu
    out1r[(size_t)w * C1 + lane] = f2bf(r);
}

// ---- K_gemm2 (MFMA, verified R9): H2 = out1r @ W2 + s2/d2 dots ----
__global__ __launch_bounds__(256) void k_gemm2(
    const ushort_t* __restrict__ out1r, const ushort_t* __restrict__ W2p,
    const float* __restrict__ as2, const float* __restrict__ ad2,
    ushort_t* __restrict__ H2, float* __restrict__ s2, float* __restrict__ d2)
{
    int tile = (blockIdx.x * blockDim.x + threadIdx.x) >> 6;
    int lane = threadIdx.x & 63;
    if (tile >= N_NODES / 16) return;
    int quad = lane >> 4, lo = lane & 15;
    const ushort_t* arow = out1r + ((size_t)tile * 16 + lo) * C1 + quad * 8;
    short8 a0 = *(const short8*)arow;
    short8 a1 = *(const short8*)(arow + 32);
    f32x4 acc[3] = {{0,0,0,0},{0,0,0,0},{0,0,0,0}};
    #pragma unroll
    for (int nt = 0; nt < 3; ++nt) {
        short8 b0 = *(const short8*)&W2p[((nt * 2 + 0) * 64 + lane) * 8];
        short8 b1 = *(const short8*)&W2p[((nt * 2 + 1) * 64 + lane) * 8];
        acc[nt] = __builtin_amdgcn_mfma_f32_16x16x32_bf16(a0, b0, acc[nt], 0, 0, 0);
        acc[nt] = __builtin_amdgcn_mfma_f32_16x16x32_bf16(a1, b1, acc[nt], 0, 0, 0);
    }
    float ps0 = 0.f, ps1 = 0.f, ps2 = 0.f, ps3 = 0.f;
    float pd0 = 0.f, pd1 = 0.f, pd2 = 0.f, pd3 = 0.f;
    #pragma unroll
    for (int nt = 0; nt < 3; ++nt) {
        int cb = nt * 16 + lo;
        float a2 = cb < C2 ? as2[cb] : 0.f;
        float b2 = cb < C2 ? ad2[cb] : 0.f;
        float v0 = acc[nt][0], v1 = acc[nt][1], v2 = acc[nt][2], v3 = acc[nt][3];
        int nb = tile * 16 + quad * 4;
        H2[(size_t)(nb + 0) * C1 + cb] = f2bf(v0);
        H2[(size_t)(nb + 1) * C1 + cb] = f2bf(v1);
        H2[(size_t)(nb + 2) * C1 + cb] = f2bf(v2);
        H2[(size_t)(nb + 3) * C1 + cb] = f2bf(v3);
        ps0 = fmaf(v0, a2, ps0); ps1 = fmaf(v1, a2, ps1);
        ps2 = fmaf(v2, a2, ps2); ps3 = fmaf(v3, a2, ps3);
        pd0 = fmaf(v0, b2, pd0); pd1 = fmaf(v1, b2, pd1);
        pd2 = fmaf(v2, b2, pd2); pd3 = fmaf(v3, b2, pd3);
    }
    #pragma unroll
    for (int off = 1; off < 16; off <<= 1) {
        ps0 += __shfl_xor(ps0, off); ps1 += __shfl_xor(ps1, off);
        ps2 += __shfl_xor(ps2, off); ps3 += __shfl_xor(ps3, off);
        pd0 += __shfl_xor(pd0, off); pd1 += __shfl_xor(pd1, off);
        pd2 += __shfl_xor(pd2, off); pd3 += __shfl_xor(pd3, off);
    }
    if (lo == 0) {
        int nb = tile * 16 + quad * 4;
        s2[nb + 0] = ps0; s2[nb + 1] = ps1; s2[nb + 2] = ps2; s2[nb + 3] = ps3;
        d2[nb + 0] = pd0; d2[nb + 1] = pd1; d2[nb + 2] = pd2; d2[nb + 3] = pd3;
    }
}

// ---- K_logit2 ----
__global__ __launch_bounds__(256) void k_logit2(
    const int* __restrict__ rowptr, const int2* __restrict__ edges,
    const float* __restrict__ s2, const float* __restrict__ d2,
    const float* __restrict__ ae2, half_t* __restrict__ p2)
{
    int w = (blockIdx.x * blockDim.x + threadIdx.x) >> 6;
    int lane = threadIdx.x & 63;
    if (w >= N_NODES) return;
    float d2v = d2[w];
    float aev = ae2[0];
    int jb = rowptr[w], je = rowptr[w + 1];
    for (int idx = jb + lane; idx < je; idx += 64) {
        int2 ed = edges[idx];
        float l = lrelu(s2[ed.x] + d2v + __int_as_float(ed.y) * aev);
        p2[idx] = (half_t)__expf(l);
    }
}

// ---- K_node2: lean 4-unroll + fused log_softmax ----
__global__ __launch_bounds__(256) void k_node2(
    const int* __restrict__ rowptr, const int2* __restrict__ edges,
    const half_t* __restrict__ p2, const ushort_t* __restrict__ H2,
    float* __restrict__ out)
{
    int w = (blockIdx.x * blockDim.x + threadIdx.x) >> 6;
    int lane = threadIdx.x & 63;
    if (w >= N_NODES) return;
    int c = lane < C2 ? lane : 0;
    int jb = rowptr[w], je = rowptr[w + 1];
    float den0 = 0.f, den1 = 0.f, den2_ = 0.f, den3 = 0.f;
    float acc0 = 0.f, acc1 = 0.f, acc2 = 0.f, acc3 = 0.f;
    int j = jb;
    for (; j + 3 < je; j += 4) {
        int s0 = edges[j].x, s1_ = edges[j + 1].x;
        int s2_ = edges[j + 2].x, s3 = edges[j + 3].x;
        float p0 = (float)p2[j], p1v = (float)p2[j + 1];
        float p2v = (float)p2[j + 2], p3 = (float)p2[j + 3];
        float h0 = bf2f(H2[(size_t)s0 * C1 + c]);
        float h1 = bf2f(H2[(size_t)s1_ * C1 + c]);
        float h2_ = bf2f(H2[(size_t)s2_ * C1 + c]);
        float h3 = bf2f(H2[(size_t)s3 * C1 + c]);
        den0 += p0; den1 += p1v; den2_ += p2v; den3 += p3;
        acc0 = fmaf(p0, h0, acc0);
        acc1 = fmaf(p1v, h1, acc1);
        acc2 = fmaf(p2v, h2_, acc2);
        acc3 = fmaf(p3, h3, acc3);
    }
    for (; j < je; ++j) {
        int s0 = edges[j].x;
        float p0 = (float)p2[j];
        den0 += p0;
        acc0 = fmaf(p0, bf2f(H2[(size_t)s0 * C1 + c]), acc0);
    }
    float den = (den0 + den1) + (den2_ + den3);
    float acc = (acc0 + acc1) + (acc2 + acc3);
    float o = acc / (den + 1e-16f);
    float v = lane < C2 ? o : -INFINITY;
    float m = v;
    #pragma unroll
    for (int off = 32; off; off >>= 1) m = fmaxf(m, __shfl_xor(m, off));
    float p = lane < C2 ? __expf(v - m) : 0.f;
    #pragma unroll
    for (int off = 32; off; off >>= 1) p += __shfl_xor(p, off);
    float ls = __logf(p);
    if (lane < C2) out[(size_t)w * C2 + lane] = v - m - ls;
}

extern "C" void kernel_launch(void* const* d_in, const int* in_sizes, int n_in,
                              void* d_out, int out_size, void* d_ws, size_t ws_size,
                              hipStream_t stream)
{
    const float* x   = (const float*)d_in[0];
    const int*   ei  = (const int*)  d_in[1];
    const float* ea  = (const float*)d_in[2];
    const float* W1  = (const float*)d_in[3];
    const float* as1 = (const float*)d_in[4];
    const float* ad1 = (const float*)d_in[5];
    const float* ae1 = (const float*)d_in[6];
    const float* W2  = (const float*)d_in[7];
    const float* as2 = (const float*)d_in[8];
    const float* ad2 = (const float*)d_in[9];
    const float* ae2 = (const float*)d_in[10];
    float* out = (float*)d_out;

    // workspace layout (4-byte units), aliased to stay <= 72 MB:
    //   H1 [0,3.2M) dead after k_node1 -> reused as H2 (k_gemm2 writes)
    //   out1r in [3.2M,6.4M)
    //   xb (bf16 x, 6.4M words) in the p1 slot [9.6M,16.0M): dead after
    //     k_gemm1_mfma; then deg/rank alias it (memset AFTER gemm1!), then
    //     p1 overwrites (k_logit1)
    //   p2 aliases s1 (dead after k_logit1)
    //   rowptr needs 100,001 ints -> s2 starts 8 words later (R5 lesson)
    float*    ws     = (float*)d_ws;
    ushort_t* H1     = (ushort_t*)ws;                 // [0, 3.2M)  bf16
    ushort_t* H2     = (ushort_t*)ws;                 //   alias (after node1)
    ushort_t* out1r  = (ushort_t*)(ws + 3200000);     // [3.2M, 6.4M)
    int2*     edges  = (int2*)(ws + 6400000);         // [6.4M, 9.6M)
    ushort_t* xb     = (ushort_t*)(ws + 9600000);     // [9.6M, 16.0M) bf16 x
    half_t*   p1     = (half_t*)(ws + 9600000);       //   alias (after gemm1)
    int*      deg    = (int*)(ws + 9600000);          //   alias (after gemm1)
    int*      rank   = (int*)(ws + 9700000);          //   alias
    int*      bsum   = (int*)(ws + 11300000);         //   alias (391)
    int*      boff   = (int*)(ws + 11301000);         //   alias (391)
    float*    s1     = ws + 16000000;                 // [16.0M, 16.8M)
    half_t*   p2     = (half_t*)(ws + 16000000);      //   alias
    float*    d1     = ws + 16800000;                 // [16.8M, 17.6M)
    int*      rowptr = (int*)(ws + 17600000);         // 100,001 ints
    float*    s2     = ws + 17700008;                 // 100,000
    float*    d2     = ws + 17800008;                 // 100,000
    ushort_t* W2p    = (ushort_t*)(ws + 17900008);    // 3072 bf16 (1536 w)
    ushort_t* W1p    = (ushort_t*)(ws + 17901544);    // 8192 bf16 (4096 w)

    k_xcast     <<<N_NODES * IN_F / (256 * 8), 256, 0, stream>>>(x, xb);
    k_w1prep    <<<32, 256, 0, stream>>>(W1, W1p);
    k_w2prep    <<<12, 256, 0, stream>>>(W2, W2p);
    k_gemm1_mfma<<<(N_NODES / 16 + 3) / 4, 256, 0, stream>>>(xb, W1p, H1);
    k_sd1       <<<(N_NODES + 3) / 4, 256, 0, stream>>>(H1, as1, ad1, s1, d1);
    hipMemsetAsync(deg, 0, 100000 * 4, stream);       // AFTER gemm1 (xb alias)
    k_count     <<<(N_EDGES + 255) / 256, 256, 0, stream>>>(ei, deg, rank);
    k_red       <<<N_SBLK, SCAN_B, 0, stream>>>(deg, bsum);
    k_scan_small<<<1, 512, 0, stream>>>(bsum, boff, rowptr);
    k_apply     <<<N_SBLK, SCAN_B, 0, stream>>>(deg, boff, rowptr);
    k_fill      <<<(N_EDGES + 255) / 256, 256, 0, stream>>>(ei, ea, rowptr, rank, edges);
    k_logit1    <<<(N_NODES + 3) / 4, 256, 0, stream>>>(rowptr, edges, s1, d1, ae1, p1);
    k_node1     <<<(N_NODES + 3) / 4, 256, 0, stream>>>(rowptr, edges, p1, H1, out1r);
    k_gemm2     <<<(N_NODES / 16 + 3) / 4, 256, 0, stream>>>(out1r, W2p, as2, ad2,
                                                             H2, s2, d2);
    k_logit2    <<<(N_NODES + 3) / 4, 256, 0, stream>>>(rowptr, edges, s2, d2, ae2, p2);
    k_node2     <<<(N_NODES + 3) / 4, 256, 0, stream>>>(rowptr, edges, p2, H2, out);
}